// Round 2
// baseline (62.759 us; speedup 1.0000x reference)
//
#include <hip/hip_runtime.h>

#define K_KNOTS 512
#define NTHREADS 256

__device__ __forceinline__ float kan_one(float xs, const float* __restrict__ gw,
                                         float C1, float C2) {
    // x0 = (x - XMIN) / (XMAX - XMIN + 1e-8); 6.0+1e-8 rounds to 6.0f in fp32
    float x0 = (xs + 3.0f) / 6.0f;
    float u = x0 * 512.0f;
    u = fmodf(u, 512.0f);
    if (u < 0.0f) u += 512.0f;          // jnp.remainder: result sign of divisor
    float fi = floorf(u);
    float t = u - fi;
    int base = (int)fi;                 // may be 512 at the wrap edge; idx is modded below

    float t2 = t * t;
    float t3 = t2 * t;
    float omt = 1.0f - t;
    float b0 = omt * omt * omt / 6.0f;
    float b1 = (3.0f * t3 - 6.0f * t2 + 4.0f) / 6.0f;
    float b2 = (-3.0f * t3 + 3.0f * t2 + 3.0f * t + 1.0f) / 6.0f;
    float b3 = t3 / 6.0f;

    // LayerNorm stats of the 4-sparse row (K-4 zeros contribute (0-mu)^2 each)
    float S = b0 + b1 + b2 + b3;
    float mu = S * (1.0f / 512.0f);
    float d0 = b0 - mu, d1 = b1 - mu, d2 = b2 - mu, d3 = b3 - mu;
    float var = (d0 * d0 + d1 * d1 + d2 * d2 + d3 * d3
                 + (512.0f - 4.0f) * (mu * mu)) * (1.0f / 512.0f);
    float rs = rsqrtf(var + 1e-5f);

    float g0 = gw[ base      & 511];
    float g1 = gw[(base + 1) & 511];
    float g2 = gw[(base + 2) & 511];
    float g3 = gw[(base + 3) & 511];
    float dot = b0 * g0 + b1 * g1 + b2 * g2 + b3 * g3;

    // y = rs * sum_k (f_k - mu)*gamma_k*w_k + sum_k beta_k*w_k + head_b
    return rs * (dot - mu * C1) + C2;
}

__global__ __launch_bounds__(NTHREADS) void kan1d_fused(
    const float* __restrict__ x,
    const float* __restrict__ ln_gamma,
    const float* __restrict__ ln_beta,
    const float* __restrict__ head_w,
    const float* __restrict__ head_b,
    float* __restrict__ out,
    int n4, int n)
{
    __shared__ float gw[K_KNOTS];
    __shared__ float red[8];
    __shared__ float sC1, sC2;

    const int tid = threadIdx.x;

    // Stage gamma*w into LDS; accumulate C1 = sum(g*w), C2 = sum(beta*w)
    float c1 = 0.0f, c2 = 0.0f;
    for (int k = tid; k < K_KNOTS; k += NTHREADS) {
        float g = ln_gamma[k];
        float w = head_w[k];
        float v = g * w;
        gw[k] = v;
        c1 += v;
        c2 += ln_beta[k] * w;
    }
#pragma unroll
    for (int off = 32; off > 0; off >>= 1) {
        c1 += __shfl_down(c1, off, 64);
        c2 += __shfl_down(c2, off, 64);
    }
    const int lane = tid & 63, wid = tid >> 6;
    if (lane == 0) { red[wid] = c1; red[4 + wid] = c2; }
    __syncthreads();
    if (tid == 0) {
        sC1 = red[0] + red[1] + red[2] + red[3];
        sC2 = red[4] + red[5] + red[6] + red[7] + head_b[0];
    }
    __syncthreads();
    const float C1 = sC1;
    const float C2 = sC2;

    const float4* __restrict__ xv4 = (const float4*)x;
    float4* __restrict__ ov4 = (float4*)out;

    for (int i = blockIdx.x * NTHREADS + tid; i < n4; i += gridDim.x * NTHREADS) {
        float4 xv = xv4[i];
        float4 yv;
        yv.x = kan_one(xv.x, gw, C1, C2);
        yv.y = kan_one(xv.y, gw, C1, C2);
        yv.z = kan_one(xv.z, gw, C1, C2);
        yv.w = kan_one(xv.w, gw, C1, C2);
        ov4[i] = yv;
    }
    // scalar tail (N % 4 != 0 safety; N=262144 has none)
    for (int i = n4 * 4 + blockIdx.x * NTHREADS + tid; i < n;
         i += gridDim.x * NTHREADS) {
        out[i] = kan_one(x[i], gw, C1, C2);
    }
}

extern "C" void kernel_launch(void* const* d_in, const int* in_sizes, int n_in,
                              void* d_out, int out_size, void* d_ws, size_t ws_size,
                              hipStream_t stream) {
    const float* x        = (const float*)d_in[0];
    const float* ln_gamma = (const float*)d_in[1];
    const float* ln_beta  = (const float*)d_in[2];
    const float* head_w   = (const float*)d_in[3];
    const float* head_b   = (const float*)d_in[4];
    float* out = (float*)d_out;

    const int n = in_sizes[0];
    const int n4 = n >> 2;

    // 256 blocks x 256 threads: 65536 threads, one float4 each at N=262144.
    kan1d_fused<<<256, NTHREADS, 0, stream>>>(x, ln_gamma, ln_beta, head_w,
                                              head_b, out, n4, n);
}

// Round 3
// 62.035 us; speedup vs baseline: 1.0117x; 1.0117x over previous
//
#include <hip/hip_runtime.h>

#define K_KNOTS 512
#define NTHREADS 256

__device__ __forceinline__ float kan_one(float xs, const float* __restrict__ gw,
                                         float C1, float C2) {
    // x0 = (x - XMIN)/(XMAX - XMIN + 1e-8); 6+1e-8 rounds to 6.0f -> divide like the ref
    float x0 = (xs + 3.0f) / 6.0f;
    // u = remainder(x0*512, 512): x0*512 is an exact pow2 scale and |x0*512| <= 256
    // for any realistic N(0,1) sample, so remainder is Sterbenz-exact and
    // frac(u) == w - floor(w), floor(u) mod 512 == (int)floor(w) & 511 (bit-exact).
    float w  = x0 * 512.0f;
    float fw = floorf(w);
    float t  = w - fw;
    int base = (int)fw;

    float t2 = t * t;
    float t3 = t2 * t;
    float omt = 1.0f - t;
    float b0 = omt * omt * omt * (1.0f / 6.0f);
    float b1 = (3.0f * t3 - 6.0f * t2 + 4.0f) * (1.0f / 6.0f);
    float b2 = (-3.0f * t3 + 3.0f * t2 + 3.0f * t + 1.0f) * (1.0f / 6.0f);
    float b3 = t3 * (1.0f / 6.0f);

    // LayerNorm stats of the 4-sparse row (K-4 zeros contribute mu^2 each)
    float S = b0 + b1 + b2 + b3;
    float mu = S * (1.0f / 512.0f);
    float d0 = b0 - mu, d1 = b1 - mu, d2 = b2 - mu, d3 = b3 - mu;
    float var = (d0 * d0 + d1 * d1 + d2 * d2 + d3 * d3
                 + 508.0f * (mu * mu)) * (1.0f / 512.0f);
    float rs = rsqrtf(var + 1e-5f);

    float g0 = gw[ base      & 511];
    float g1 = gw[(base + 1) & 511];
    float g2 = gw[(base + 2) & 511];
    float g3 = gw[(base + 3) & 511];
    float dot = b0 * g0 + b1 * g1 + b2 * g2 + b3 * g3;

    return rs * (dot - mu * C1) + C2;
}

__global__ __launch_bounds__(NTHREADS) void kan1d_fused(
    const float* __restrict__ x,
    const float* __restrict__ ln_gamma,
    const float* __restrict__ ln_beta,
    const float* __restrict__ head_w,
    const float* __restrict__ head_b,
    float* __restrict__ out,
    int n4, int n)
{
    __shared__ float gw[K_KNOTS];
    __shared__ float red[8];
    __shared__ float sC1, sC2;

    const int tid = threadIdx.x;
    const int gi = blockIdx.x * NTHREADS + tid;

    // Issue the x load FIRST so its HBM latency hides under the param prologue.
    const float4* __restrict__ xv4 = (const float4*)x;
    float4 xv;
    const bool valid = gi < n4;
    if (valid) xv = xv4[gi];

    // Stage gamma*w into LDS; accumulate C1 = sum(g*w), C2 = sum(beta*w)
    float c1 = 0.0f, c2 = 0.0f;
    for (int k = tid; k < K_KNOTS; k += NTHREADS) {
        float g = ln_gamma[k];
        float hw = head_w[k];
        float v = g * hw;
        gw[k] = v;
        c1 += v;
        c2 += ln_beta[k] * hw;
    }
#pragma unroll
    for (int off = 32; off > 0; off >>= 1) {
        c1 += __shfl_down(c1, off, 64);
        c2 += __shfl_down(c2, off, 64);
    }
    const int lane = tid & 63, wid = tid >> 6;
    if (lane == 0) { red[wid] = c1; red[4 + wid] = c2; }
    __syncthreads();
    if (tid == 0) {
        sC1 = red[0] + red[1] + red[2] + red[3];
        sC2 = red[4] + red[5] + red[6] + red[7] + head_b[0];
    }
    __syncthreads();
    const float C1 = sC1;
    const float C2 = sC2;

    if (valid) {
        float4 yv;
        yv.x = kan_one(xv.x, gw, C1, C2);
        yv.y = kan_one(xv.y, gw, C1, C2);
        yv.z = kan_one(xv.z, gw, C1, C2);
        yv.w = kan_one(xv.w, gw, C1, C2);
        ((float4*)out)[gi] = yv;
    }
    // scalar tail (N % 4 != 0 safety; N=262144 has none)
    for (int i = n4 * 4 + gi; i < n; i += gridDim.x * NTHREADS) {
        out[i] = kan_one(x[i], gw, C1, C2);
    }
}

extern "C" void kernel_launch(void* const* d_in, const int* in_sizes, int n_in,
                              void* d_out, int out_size, void* d_ws, size_t ws_size,
                              hipStream_t stream) {
    const float* x        = (const float*)d_in[0];
    const float* ln_gamma = (const float*)d_in[1];
    const float* ln_beta  = (const float*)d_in[2];
    const float* head_w   = (const float*)d_in[3];
    const float* head_b   = (const float*)d_in[4];
    float* out = (float*)d_out;

    const int n = in_sizes[0];
    const int n4 = n >> 2;
    const int nblocks = (n4 + NTHREADS - 1) / NTHREADS;  // 256 at N=262144

    kan1d_fused<<<nblocks, NTHREADS, 0, stream>>>(x, ln_gamma, ln_beta, head_w,
                                                  head_b, out, n4, n);
}